// Round 7
// baseline (113.228 us; speedup 1.0000x reference)
//
#include <hip/hip_runtime.h>
#include <hip/hip_fp16.h>
#include <stdint.h>

#define NPTS 2097152
#define BLOCK 256
#define PPT 4
#define TILES 2
#define NBLK (NPTS / (BLOCK * PPT * TILES))   // 1024 blocks

static __device__ __forceinline__ float silu_f(float v) {
    return v * __builtin_amdgcn_rcpf(1.0f + __expf(-v));
}
static __device__ __forceinline__ __half2 u2h(uint32_t u) {
    union { uint32_t i; __half2 h; } v; v.i = u; return v.h;
}
static __device__ __forceinline__ uint32_t h2u(__half2 h) {
    union { __half2 h; uint32_t i; } v; v.h = h; return v.i;
}

__global__ __launch_bounds__(BLOCK, 4) void camfield_kernel(
    const float* __restrict__ xy,
    const float* __restrict__ gamma,
    const float* __restrict__ beta,
    const float* __restrict__ w_in,
    const float* __restrict__ b_in,
    const float* __restrict__ w_h,
    const float* __restrict__ b_h,
    const float* __restrict__ w_out,
    const float* __restrict__ b_out,
    const float* __restrict__ ln_w,
    const float* __restrict__ ln_b,
    float* __restrict__ out)
{
    // LDS: x-duplicated cell lines, ln_w pre-folded into gamma.
    // Per cell (y,x): 6 half2 pairs s stored as [A_s(x), B_s(x+1 clamped)],
    // dwords {A0,B0,...,A5,B5} = 48 B/cell. One bilinear patch = 3x b128 at
    // cell + 3x b128 at +768 B (row y0+1); layer 1 at +12288 B (imm reach).
    __shared__ __align__(16) uint32_t sg[2][256][12];

    const int tid = threadIdx.x;
    const int blockBase = blockIdx.x * (BLOCK * PPT * TILES);
    const int p0a = blockBase + tid * PPT;                    // tile 0
    const int p0b = blockBase + BLOCK * PPT + tid * PPT;      // tile 1

    // ---- prefetch tile-0 xy before staging (HBM latency hidden by staging)
    const float4* xva = (const float4*)(xy + 2 * p0a);
    float4 qa0 = xva[0];
    float4 qa1 = xva[1];

    // ---- stage grids: fp32 global -> packed half2 LDS (gamma *= ln_w).
    // layer stride 1536 is NOT pow2 — decompose by compare.
    for (int idx = tid; idx < 3072; idx += BLOCK) {
        int l = (idx >= 1536) ? 1 : 0;
        int r = idx - l * 1536;            // 0..1535
        int s = r >> 8;                    // pair 0..5
        int cell = r & 255;
        int x = cell & 15;
        int x1 = (x < 15) ? x + 1 : 15;    // border clamp baked into B
        int rowb = cell - x;               // y*16
        const float* src;
        float m_lo, m_hi;
        if (s < 3) {
            src = gamma + l * 1536 + (2 * s) * 256;
            m_lo = ln_w[l * 6 + 2 * s];
            m_hi = ln_w[l * 6 + 2 * s + 1];
        } else {
            src = beta + l * 1536 + (2 * (s - 3)) * 256;
            m_lo = 1.0f; m_hi = 1.0f;
        }
        float a_lo = src[rowb + x] * m_lo;
        float a_hi = src[256 + rowb + x] * m_hi;
        float b_lo = src[rowb + x1] * m_lo;
        float b_hi = src[256 + rowb + x1] * m_hi;
        sg[l][cell][2 * s]     = h2u(__floats2half2_rn(a_lo, a_hi));
        sg[l][cell][2 * s + 1] = h2u(__floats2half2_rn(b_lo, b_hi));
    }

    // ---- weights to registers (wave-uniform; scalarized)
    float Win0[6], Win1[6], Bin[6], Wh[6][6], Bh[6], Wo[3][6], Bo[3], K[2][6];
#pragma unroll
    for (int j = 0; j < 6; ++j) {
        Win0[j] = w_in[2 * j];
        Win1[j] = w_in[2 * j + 1];
        Bin[j]  = b_in[j];
        Bh[j]   = b_h[j];
#pragma unroll
        for (int k = 0; k < 6; ++k) Wh[j][k] = w_h[6 * j + k];
        K[0][j] = ln_b[j] / ln_w[j];          // FiLM: gl'*(d*rs + K) + bl
        K[1][j] = ln_b[6 + j] / ln_w[6 + j];
    }
#pragma unroll
    for (int j = 0; j < 3; ++j) {
        Bo[j] = b_out[j];
#pragma unroll
        for (int k = 0; k < 6; ++k) Wo[j][k] = w_out[6 * j + k];
    }

    __syncthreads();

    // ---- prefetch tile-1 xy (completes during tile-0 compute)
    const float4* xvb = (const float4*)(xy + 2 * p0b);
    float4 qb0 = xvb[0];
    float4 qb1 = xvb[1];

    auto process4 = [&](float4 Q0, float4 Q1, int p0) {
        float xs[4] = { Q0.x, Q0.z, Q1.x, Q1.z };
        float ys[4] = { Q0.y, Q0.w, Q1.y, Q1.w };
        float o[3 * PPT];

#pragma unroll
        for (int p = 0; p < PPT; ++p) {
            const float x = xs[p];
            const float y = ys[p];

            float fx = fminf(fmaxf(fmaf(x, 7.5f, 7.5f), 0.0f), 15.0f);
            float fy = fminf(fmaxf(fmaf(y, 7.5f, 7.5f), 0.0f), 15.0f);
            int x0 = (int)fx; if (x0 > 14) x0 = 14;
            int y0 = (int)fy; if (y0 > 14) y0 = 14;
            float wx = fx - (float)x0;
            float wy = fy - (float)y0;
            float w11f = wx * wy;
            float w10f = wy - w11f;
            float w01f = wx - w11f;
            float w00f = 1.0f - wx - wy + w11f;

            const __half2 W00 = __float2half2_rn(w00f);
            const __half2 W01 = __float2half2_rn(w01f);
            const __half2 W10 = __float2half2_rn(w10f);
            const __half2 W11 = __float2half2_rn(w11f);

            const int cell = (y0 << 4) + x0;

            float gl[2][6], bl[2][6];
#pragma unroll
            for (int l = 0; l < 2; ++l) {
                const uint4* c4 = (const uint4*)&sg[l][cell][0];
                uint4 u0 = c4[0];
                uint4 u1 = c4[1];
                uint4 u2 = c4[2];
                uint4 v0 = c4[48];   // +768 B: row y0+1
                uint4 v1 = c4[49];
                uint4 v2 = c4[50];

                uint32_t A[6] = { u0.x, u0.z, u1.x, u1.z, u2.x, u2.z };
                uint32_t B[6] = { u0.y, u0.w, u1.y, u1.w, u2.y, u2.w };
                uint32_t C[6] = { v0.x, v0.z, v1.x, v1.z, v2.x, v2.z };
                uint32_t D[6] = { v0.y, v0.w, v1.y, v1.w, v2.y, v2.w };

                float2 r[6];
#pragma unroll
                for (int s = 0; s < 6; ++s) {
                    __half2 acc = __hmul2(u2h(A[s]), W00);
                    acc = __hfma2(u2h(B[s]), W01, acc);
                    acc = __hfma2(u2h(C[s]), W10, acc);
                    acc = __hfma2(u2h(D[s]), W11, acc);
                    r[s] = __half22float2(acc);
                }
                gl[l][0] = r[0].x; gl[l][1] = r[0].y;
                gl[l][2] = r[1].x; gl[l][3] = r[1].y;
                gl[l][4] = r[2].x; gl[l][5] = r[2].y;
                bl[l][0] = r[3].x; bl[l][1] = r[3].y;
                bl[l][2] = r[4].x; bl[l][3] = r[4].y;
                bl[l][4] = r[5].x; bl[l][5] = r[5].y;
            }

            // input layer
            float h[6];
#pragma unroll
            for (int j = 0; j < 6; ++j)
                h[j] = silu_f(fmaf(x, Win0[j], fmaf(y, Win1[j], Bin[j])));

            // layer 0: h = gl'*(d*rs + K) + bl   (lnw folded into gl')
            {
                float mu = (h[0] + h[1] + h[2] + h[3] + h[4] + h[5]) * (1.0f / 6.0f);
                float d[6], var = 0.0f;
#pragma unroll
                for (int j = 0; j < 6; ++j) { d[j] = h[j] - mu; var = fmaf(d[j], d[j], var); }
                var *= (1.0f / 6.0f);
                float rs = __builtin_amdgcn_rsqf(var + 1e-5f);
#pragma unroll
                for (int j = 0; j < 6; ++j)
                    h[j] = fmaf(gl[0][j], fmaf(d[j], rs, K[0][j]), bl[0][j]);
            }

            // hidden layer
            float t[6];
#pragma unroll
            for (int j = 0; j < 6; ++j) {
                float a = Bh[j];
#pragma unroll
                for (int k = 0; k < 6; ++k) a = fmaf(h[k], Wh[j][k], a);
                t[j] = silu_f(a);
            }

            // layer 1
            {
                float mu = (t[0] + t[1] + t[2] + t[3] + t[4] + t[5]) * (1.0f / 6.0f);
                float d[6], var = 0.0f;
#pragma unroll
                for (int j = 0; j < 6; ++j) { d[j] = t[j] - mu; var = fmaf(d[j], d[j], var); }
                var *= (1.0f / 6.0f);
                float rs = __builtin_amdgcn_rsqf(var + 1e-5f);
#pragma unroll
                for (int j = 0; j < 6; ++j)
                    t[j] = fmaf(gl[1][j], fmaf(d[j], rs, K[1][j]), bl[1][j]);
            }

            // output layer
#pragma unroll
            for (int j = 0; j < 3; ++j) {
                float a = Bo[j];
#pragma unroll
                for (int k = 0; k < 6; ++k) a = fmaf(t[k], Wo[j][k], a);
                o[3 * p + j] = a;
            }
        }

        float4* op = (float4*)(out + 3 * p0);
#pragma unroll
        for (int q = 0; q < 3; ++q)
            op[q] = make_float4(o[4 * q], o[4 * q + 1], o[4 * q + 2], o[4 * q + 3]);
    };

    process4(qa0, qa1, p0a);
    process4(qb0, qb1, p0b);
}

extern "C" void kernel_launch(void* const* d_in, const int* in_sizes, int n_in,
                              void* d_out, int out_size, void* d_ws, size_t ws_size,
                              hipStream_t stream) {
    camfield_kernel<<<NBLK, BLOCK, 0, stream>>>(
        (const float*)d_in[0],  // xy
        (const float*)d_in[1],  // gamma
        (const float*)d_in[2],  // beta
        (const float*)d_in[3],  // w_in
        (const float*)d_in[4],  // b_in
        (const float*)d_in[5],  // w_h
        (const float*)d_in[6],  // b_h
        (const float*)d_in[7],  // w_out
        (const float*)d_in[8],  // b_out
        (const float*)d_in[9],  // ln_w
        (const float*)d_in[10], // ln_b
        (float*)d_out);
}

// Round 8
// 113.089 us; speedup vs baseline: 1.0012x; 1.0012x over previous
//
#include <hip/hip_runtime.h>
#include <hip/hip_fp16.h>
#include <stdint.h>

#define NPTS 2097152
#define BLOCK 256
#define PPT 4
#define NBLK (NPTS / (BLOCK * PPT))   // 2048 blocks

static __device__ __forceinline__ float silu_f(float v) {
    return v * __builtin_amdgcn_rcpf(1.0f + __expf(-v));
}
static __device__ __forceinline__ __half2 u2h(uint32_t u) {
    union { uint32_t i; __half2 h; } v; v.i = u; return v.h;
}
static __device__ __forceinline__ uint32_t h2u(__half2 h) {
    union { __half2 h; uint32_t i; } v; v.h = h; return v.i;
}

__global__ __launch_bounds__(BLOCK, 4) void camfield_kernel(
    const float* __restrict__ xy,
    const float* __restrict__ gamma,
    const float* __restrict__ beta,
    const float* __restrict__ w_in,
    const float* __restrict__ b_in,
    const float* __restrict__ w_h,
    const float* __restrict__ b_h,
    const float* __restrict__ w_out,
    const float* __restrict__ b_out,
    const float* __restrict__ ln_w,
    const float* __restrict__ ln_b,
    float* __restrict__ out)
{
    // LDS: x-duplicated cell lines, ln_w pre-folded into gamma.
    // Per cell (y,x): 6 half2 pairs s stored as [A_s(x), B_s(x+1 clamped)],
    // dwords {A0,B0,...,A5,B5} = 48 B/cell. One bilinear patch = 3x b128 at
    // cell + 3x b128 at +768 B (row y0+1). 24 KB total.
    __shared__ __align__(16) uint32_t sg[2][256][12];

    const int tid = threadIdx.x;
    const int p0 = (blockIdx.x * BLOCK + tid) * PPT;

    // ---- prefetch xy before staging (HBM latency hidden by staging)
    const float4* xv = (const float4*)(xy + 2 * p0);
    float4 q0 = xv[0];
    float4 q1 = xv[1];

    // ---- stage grids: fp32 global -> packed half2 LDS (gamma *= ln_w).
    // layer stride 1536 is NOT pow2 — decompose by compare.
    for (int idx = tid; idx < 3072; idx += BLOCK) {
        int l = (idx >= 1536) ? 1 : 0;
        int r = idx - l * 1536;            // 0..1535
        int s = r >> 8;                    // pair 0..5
        int cell = r & 255;
        int x = cell & 15;
        int x1 = (x < 15) ? x + 1 : 15;    // border clamp baked into B
        int rowb = cell - x;               // y*16
        const float* src;
        float m_lo, m_hi;
        if (s < 3) {
            src = gamma + l * 1536 + (2 * s) * 256;
            m_lo = ln_w[l * 6 + 2 * s];
            m_hi = ln_w[l * 6 + 2 * s + 1];
        } else {
            src = beta + l * 1536 + (2 * (s - 3)) * 256;
            m_lo = 1.0f; m_hi = 1.0f;
        }
        float a_lo = src[rowb + x] * m_lo;
        float a_hi = src[256 + rowb + x] * m_hi;
        float b_lo = src[rowb + x1] * m_lo;
        float b_hi = src[256 + rowb + x1] * m_hi;
        sg[l][cell][2 * s]     = h2u(__floats2half2_rn(a_lo, a_hi));
        sg[l][cell][2 * s + 1] = h2u(__floats2half2_rn(b_lo, b_hi));
    }

    // ---- weights to registers (wave-uniform; scalarized)
    float Win0[6], Win1[6], Bin[6], Wh[6][6], Bh[6], Wo[3][6], Bo[3], K[2][6];
#pragma unroll
    for (int j = 0; j < 6; ++j) {
        Win0[j] = w_in[2 * j];
        Win1[j] = w_in[2 * j + 1];
        Bin[j]  = b_in[j];
        Bh[j]   = b_h[j];
#pragma unroll
        for (int k = 0; k < 6; ++k) Wh[j][k] = w_h[6 * j + k];
        K[0][j] = ln_b[j] / ln_w[j];          // FiLM: gl'*(d*rs + K) + bl
        K[1][j] = ln_b[6 + j] / ln_w[6 + j];
    }
#pragma unroll
    for (int j = 0; j < 3; ++j) {
        Bo[j] = b_out[j];
#pragma unroll
        for (int k = 0; k < 6; ++k) Wo[j][k] = w_out[6 * j + k];
    }

    __syncthreads();

    float xs[4] = { q0.x, q0.z, q1.x, q1.z };
    float ys[4] = { q0.y, q0.w, q1.y, q1.w };
    float o[3 * PPT];

#pragma unroll
    for (int p = 0; p < PPT; ++p) {
        const float x = xs[p];
        const float y = ys[p];

        float fx = fminf(fmaxf(fmaf(x, 7.5f, 7.5f), 0.0f), 15.0f);
        float fy = fminf(fmaxf(fmaf(y, 7.5f, 7.5f), 0.0f), 15.0f);
        int x0 = (int)fx; if (x0 > 14) x0 = 14;
        int y0 = (int)fy; if (y0 > 14) y0 = 14;
        float wx = fx - (float)x0;
        float wy = fy - (float)y0;
        float w11f = wx * wy;
        float w10f = wy - w11f;
        float w01f = wx - w11f;
        float w00f = 1.0f - wx - wy + w11f;

        const __half2 W00 = __float2half2_rn(w00f);
        const __half2 W01 = __float2half2_rn(w01f);
        const __half2 W10 = __float2half2_rn(w10f);
        const __half2 W11 = __float2half2_rn(w11f);

        const int cell = (y0 << 4) + x0;

        float gl[2][6], bl[2][6];
#pragma unroll
        for (int l = 0; l < 2; ++l) {
            const uint4* c4 = (const uint4*)&sg[l][cell][0];
            uint4 u0 = c4[0];
            uint4 u1 = c4[1];
            uint4 u2 = c4[2];
            uint4 v0 = c4[48];   // +768 B: row y0+1
            uint4 v1 = c4[49];
            uint4 v2 = c4[50];

            uint32_t A[6] = { u0.x, u0.z, u1.x, u1.z, u2.x, u2.z };
            uint32_t B[6] = { u0.y, u0.w, u1.y, u1.w, u2.y, u2.w };
            uint32_t C[6] = { v0.x, v0.z, v1.x, v1.z, v2.x, v2.z };
            uint32_t D[6] = { v0.y, v0.w, v1.y, v1.w, v2.y, v2.w };

            float2 r[6];
#pragma unroll
            for (int s = 0; s < 6; ++s) {
                __half2 acc = __hmul2(u2h(A[s]), W00);
                acc = __hfma2(u2h(B[s]), W01, acc);
                acc = __hfma2(u2h(C[s]), W10, acc);
                acc = __hfma2(u2h(D[s]), W11, acc);
                r[s] = __half22float2(acc);
            }
            gl[l][0] = r[0].x; gl[l][1] = r[0].y;
            gl[l][2] = r[1].x; gl[l][3] = r[1].y;
            gl[l][4] = r[2].x; gl[l][5] = r[2].y;
            bl[l][0] = r[3].x; bl[l][1] = r[3].y;
            bl[l][2] = r[4].x; bl[l][3] = r[4].y;
            bl[l][4] = r[5].x; bl[l][5] = r[5].y;
        }

        // input layer
        float h[6];
#pragma unroll
        for (int j = 0; j < 6; ++j)
            h[j] = silu_f(fmaf(x, Win0[j], fmaf(y, Win1[j], Bin[j])));

        // layer 0: h = gl'*(d*rs + K) + bl   (lnw folded into gl')
        {
            float mu = (h[0] + h[1] + h[2] + h[3] + h[4] + h[5]) * (1.0f / 6.0f);
            float d[6], var = 0.0f;
#pragma unroll
            for (int j = 0; j < 6; ++j) { d[j] = h[j] - mu; var = fmaf(d[j], d[j], var); }
            var *= (1.0f / 6.0f);
            float rs = __builtin_amdgcn_rsqf(var + 1e-5f);
#pragma unroll
            for (int j = 0; j < 6; ++j)
                h[j] = fmaf(gl[0][j], fmaf(d[j], rs, K[0][j]), bl[0][j]);
        }

        // hidden layer
        float t[6];
#pragma unroll
        for (int j = 0; j < 6; ++j) {
            float a = Bh[j];
#pragma unroll
            for (int k = 0; k < 6; ++k) a = fmaf(h[k], Wh[j][k], a);
            t[j] = silu_f(a);
        }

        // layer 1
        {
            float mu = (t[0] + t[1] + t[2] + t[3] + t[4] + t[5]) * (1.0f / 6.0f);
            float d[6], var = 0.0f;
#pragma unroll
            for (int j = 0; j < 6; ++j) { d[j] = t[j] - mu; var = fmaf(d[j], d[j], var); }
            var *= (1.0f / 6.0f);
            float rs = __builtin_amdgcn_rsqf(var + 1e-5f);
#pragma unroll
            for (int j = 0; j < 6; ++j)
                t[j] = fmaf(gl[1][j], fmaf(d[j], rs, K[1][j]), bl[1][j]);
        }

        // output layer
#pragma unroll
        for (int j = 0; j < 3; ++j) {
            float a = Bo[j];
#pragma unroll
            for (int k = 0; k < 6; ++k) a = fmaf(t[k], Wo[j][k], a);
            o[3 * p + j] = a;
        }
    }

    // store 12 fp32 = 48 B per thread, 16B-aligned
    float4* op = (float4*)(out + 3 * p0);
#pragma unroll
    for (int q = 0; q < 3; ++q)
        op[q] = make_float4(o[4 * q], o[4 * q + 1], o[4 * q + 2], o[4 * q + 3]);
}

extern "C" void kernel_launch(void* const* d_in, const int* in_sizes, int n_in,
                              void* d_out, int out_size, void* d_ws, size_t ws_size,
                              hipStream_t stream) {
    camfield_kernel<<<NBLK, BLOCK, 0, stream>>>(
        (const float*)d_in[0],  // xy
        (const float*)d_in[1],  // gamma
        (const float*)d_in[2],  // beta
        (const float*)d_in[3],  // w_in
        (const float*)d_in[4],  // b_in
        (const float*)d_in[5],  // w_h
        (const float*)d_in[6],  // b_h
        (const float*)d_in[7],  // w_out
        (const float*)d_in[8],  // b_out
        (const float*)d_in[9],  // ln_w
        (const float*)d_in[10], // ln_b
        (float*)d_out);
}